// Round 1
// 503.871 us; speedup vs baseline: 1.2547x; 1.2547x over previous
//
#include <hip/hip_runtime.h>

// AUGRU fused scan, MI355X/gfx950.  R5: MFMA rewrite.
//
// R4 post-mortem: MfmaUtil=0, VALUBusy=44%, Occupancy=13% -> VALU-latency-bound
// with the matrix pipe idle; the dot2 path's floor (~167us) is unreachable at
// 1 wave/SIMD (320 unified regs). Rewrite: 16 sequences/block, per-step matvecs
// as mfma_f32_16x16x32_f16, N split across 4 waves (12 MFMA/wave/step, weights
// 48 dwords/lane in regs). 256 blocks = 1/CU.
//
// Layouts: A/B frag k = (lane>>4)*8+j contiguous; C/D col=lane&15,
// row=(lane>>4)*4+reg (learn_hip m89/m91). h kept in C-layout regs by its
// owner wave; x/h/r*h staged in 16x64-f16 LDS tiles with XOR swizzle
// byte ^= (row&7)<<4 (else 16-way bank conflict on ds_read_b128 frags).

typedef _Float16 half4_t __attribute__((ext_vector_type(4)));
typedef _Float16 half8_t __attribute__((ext_vector_type(8)));
typedef float    f32x4  __attribute__((ext_vector_type(4)));

#define T_MAX 200
#define H_DIM 64
#define M_TILE 16

__device__ __forceinline__ f32x4 mfma16(half8_t a, half8_t b, f32x4 c) {
    return __builtin_amdgcn_mfma_f32_16x16x32_f16(a, b, c, 0, 0, 0);
}

// byte address into a [16 rows][64 f16] LDS tile, bank-conflict swizzled
__device__ __forceinline__ int swz(int row, int byteInRow) {
    return (row * 128 + byteInRow) ^ ((row & 7) << 4);
}

__global__ __launch_bounds__(256, 1) void augru_mfma(
    const float* __restrict__ X,    // (B,200,64) fp32
    const int*   __restrict__ SL,   // (B,1) int32
    const float* __restrict__ ATT,  // (B,200,1) fp32
    const float* __restrict__ WG,   // (128,128) fp32
    const float* __restrict__ BG,   // (128,) fp32
    const float* __restrict__ WC,   // (128,64) fp32
    const float* __restrict__ BC,   // (64,) fp32
    float*       __restrict__ OUT)  // (B,200,64) fp32
{
    const int tid = threadIdx.x;
    const int w   = tid >> 6;      // wave 0..3
    const int l   = tid & 63;
    const int lr  = l & 15;        // frag row (A) / col (B,C)
    const int lg  = l >> 4;        // frag k-group / row-group
    const int b0  = blockIdx.x * M_TILE;

    __shared__ float     att_s[M_TILE][T_MAX];   // 12800 B
    __shared__ int       sl_s[M_TILE];
    __shared__ _Float16  xb[2][M_TILE * 64];     // x(t) dbuf, swizzled
    __shared__ _Float16  hb[M_TILE * 64];        // h(t), swizzled
    __shared__ _Float16  rhb[M_TILE * 64];       // r*h, swizzled
    __shared__ float     ub[M_TILE][65];         // u-hat, f32, padded stride

    // ---- prologue: stage att, seq_len, zero h, stage x(0) ----
#pragma unroll
    for (int k = 0; k < 4; ++k) {
        int r = 4 * w + k;
        const float* ap = ATT + (size_t)(b0 + r) * T_MAX;
        for (int c = l; c < T_MAX; c += 64) att_s[r][c] = ap[c];
    }
    if (tid < M_TILE) {
        int v = SL[b0 + tid];
        sl_s[tid] = v < 0 ? 0 : (v > T_MAX ? T_MAX : v);
    }
    for (int i = tid; i < M_TILE * 64; i += 256) hb[i] = (_Float16)0.0f;
    {
        int r = tid >> 4, q = tid & 15;
        float4 v = *(const float4*)(X + ((size_t)(b0 + r) * T_MAX) * 64 + 4 * q);
        half4_t h4 = { (_Float16)v.x, (_Float16)v.y, (_Float16)v.z, (_Float16)v.w };
        *(half4_t*)((char*)xb[0] + swz(r, q * 8)) = h4;
    }

    // ---- weights -> B fragments (one-time; 48 dwords/lane) ----
    half8_t wg[2][4];          // [n-tile][k-tile], gate tiles g = 2w, 2w+1
    half8_t wc[4];             // cand tile w
    float   bias_g[2], bias_c;
#pragma unroll
    for (int n = 0; n < 2; ++n) {
        int col = 16 * (2 * w + n) + lr;
#pragma unroll
        for (int kt = 0; kt < 4; ++kt) {
            int kbase = 32 * kt + 8 * lg;
            half8_t f;
#pragma unroll
            for (int j = 0; j < 8; ++j) f[j] = (_Float16)WG[(size_t)(kbase + j) * 128 + col];
            wg[n][kt] = f;
        }
        bias_g[n] = BG[col];
    }
    {
        int col = 16 * w + lr;
#pragma unroll
        for (int kt = 0; kt < 4; ++kt) {
            int kbase = 32 * kt + 8 * lg;
            half8_t f;
#pragma unroll
            for (int j = 0; j < 8; ++j) f[j] = (_Float16)WC[(size_t)(kbase + j) * 64 + col];
            wc[kt] = f;
        }
        bias_c = BC[col];
    }

    __syncthreads();

    int Lmax = 0;
#pragma unroll
    for (int r = 0; r < M_TILE; ++r) Lmax = max(Lmax, sl_s[r]);
    int Lrow[4];
#pragma unroll
    for (int k = 0; k < 4; ++k) Lrow[k] = sl_s[4 * lg + k];   // cand-owner rows

    float hown[4] = {0.f, 0.f, 0.f, 0.f};   // h in C-layout, rows 4*lg+reg, col 16w+lr
    const int ccol = 16 * w + lr;

    for (int t = 0; t < Lmax; ++t) {
        const int pb = t & 1;

        // prefetch x(t+1) (always in-bounds: t+1 <= 199)
        int tn = t + 1; if (tn > T_MAX - 1) tn = T_MAX - 1;
        const int xr = tid >> 4, xq = tid & 15;
        float4 xv = *(const float4*)(X + ((size_t)(b0 + xr) * T_MAX + tn) * 64 + 4 * xq);

        // ---- phase 1: A fragments + gate MFMA (2 N-tiles x K=128) ----
        char* xbase = (char*)xb[pb];
        half8_t ax0 = *(half8_t*)(xbase + swz(lr, lg * 16));
        half8_t ax1 = *(half8_t*)(xbase + swz(lr, 64 + lg * 16));
        half8_t ah0 = *(half8_t*)((char*)hb + swz(lr, lg * 16));
        half8_t ah1 = *(half8_t*)((char*)hb + swz(lr, 64 + lg * 16));

        f32x4 accg[2];
#pragma unroll
        for (int n = 0; n < 2; ++n) {
            f32x4 acc = { bias_g[n], bias_g[n], bias_g[n], bias_g[n] };
            acc = mfma16(ax0, wg[n][0], acc);
            acc = mfma16(ax1, wg[n][1], acc);
            acc = mfma16(ah0, wg[n][2], acc);
            acc = mfma16(ah1, wg[n][3], acc);
            accg[n] = acc;
        }

        // ---- phase 2: sigmoid + exchange (waves 0,1: r*h ; waves 2,3: u-hat) ----
        if (w < 2) {
#pragma unroll
            for (int n = 0; n < 2; ++n) {
                int col = 16 * (2 * w + n) + lr;
#pragma unroll
                for (int reg = 0; reg < 4; ++reg) {
                    int row = 4 * lg + reg;
                    float rr = __fdividef(1.f, 1.f + __expf(-accg[n][reg]));
                    float hv = (float)(*(_Float16*)((char*)hb + swz(row, col * 2)));
                    *(_Float16*)((char*)rhb + swz(row, col * 2)) = (_Float16)(rr * hv);
                }
            }
        } else {
#pragma unroll
            for (int reg = 0; reg < 4; ++reg) {
                int row = 4 * lg + reg;
                float a = att_s[row][t];
#pragma unroll
                for (int n = 0; n < 2; ++n) {
                    int ucol = 16 * (2 * (w - 2) + n) + lr;   // u col = global col - 64
                    float uu = __fdividef(1.f, 1.f + __expf(-accg[n][reg]));
                    ub[row][ucol] = (1.f - a) * uu;
                }
            }
        }
        __syncthreads();   // B2: rhb/ub ready; hb reads done before hb rewrite

        // ---- phase 3: cand MFMA, tanh, h update, stores ----
        half8_t ar0 = *(half8_t*)((char*)rhb + swz(lr, lg * 16));
        half8_t ar1 = *(half8_t*)((char*)rhb + swz(lr, 64 + lg * 16));
        f32x4 accc = { bias_c, bias_c, bias_c, bias_c };
        accc = mfma16(ax0, wc[0], accc);
        accc = mfma16(ax1, wc[1], accc);
        accc = mfma16(ar0, wc[2], accc);
        accc = mfma16(ar1, wc[3], accc);

#pragma unroll
        for (int reg = 0; reg < 4; ++reg) {
            int row = 4 * lg + reg;
            float z  = accc[reg];
            float az = fabsf(z);
            float e2 = __expf(2.f * az);
            float c  = copysignf(1.f - __fdividef(2.f, e2 + 1.f), z);
            float uu = ub[row][ccol];
            float hn = uu * hown[reg] + (1.f - uu) * c;
            bool  m  = (t < Lrow[reg]);
            OUT[((size_t)(b0 + row) * T_MAX + t) * 64 + ccol] = m ? hn : 0.f;
            if (m) hown[reg] = hn;
            *(_Float16*)((char*)hb + swz(row, ccol * 2)) = (_Float16)hown[reg];
        }

        // stage x(t+1) into the other buffer
        {
            half4_t h4 = { (_Float16)xv.x, (_Float16)xv.y, (_Float16)xv.z, (_Float16)xv.w };
            *(half4_t*)((char*)xb[pb ^ 1] + swz(xr, xq * 8)) = h4;
        }
        __syncthreads();   // B3: hb(t+1), x(t+1) ready
    }

    // ---- zero-fill t in [Lmax, 200) for all 16 rows (16B stores) ----
    {
        uint4 z = make_uint4(0u, 0u, 0u, 0u);
#pragma unroll
        for (int k = 0; k < 4; ++k) {
            int r = 4 * w + k;
            uint4* zp = (uint4*)(OUT + ((size_t)(b0 + r) * T_MAX + Lmax) * 64);
            const int n4 = (T_MAX - Lmax) * (H_DIM / 4);
            for (int i = l; i < n4; i += 64) zp[i] = z;
        }
    }
}

extern "C" void kernel_launch(void* const* d_in, const int* in_sizes, int n_in,
                              void* d_out, int out_size, void* d_ws, size_t ws_size,
                              hipStream_t stream) {
    const float* X   = (const float*)d_in[0];
    const int*   SL  = (const int*)d_in[1];
    const float* ATT = (const float*)d_in[2];
    const float* WG  = (const float*)d_in[3];
    const float* BG  = (const float*)d_in[4];
    const float* WC  = (const float*)d_in[5];
    const float* BC  = (const float*)d_in[6];
    float*       OUT = (float*)d_out;

    const int B = in_sizes[1];   // sequence_length has B*1 elements
    dim3 grid(B / M_TILE), block(256);
    augru_mfma<<<grid, block, 0, stream>>>(X, SL, ATT, WG, BG, WC, BC, OUT);
}